// Round 3
// baseline (671.695 us; speedup 1.0000x reference)
//
#include <hip/hip_runtime.h>

// ---------- constants ----------
#define SLEN 2048
#define NROW 4096           // B*S
#define NH   16
#define SCALE_QK 0.07216878364870322f   // 192^-0.5
#define RMS_EPS 1.1920928955078125e-07f

typedef __attribute__((ext_vector_type(8))) short bf16x8;
typedef __attribute__((ext_vector_type(4))) float f32x4;

__device__ __forceinline__ float b2f(short s) {
  union { float f; unsigned u; } x; x.u = ((unsigned)(unsigned short)s) << 16; return x.f;
}
__device__ __forceinline__ short f2b(float f) {
  union { float f; unsigned u; } x; x.f = f;
  unsigned r = x.u + 0x7FFFu + ((x.u >> 16) & 1u);   // RNE
  return (short)(r >> 16);
}

#define GLOAD_LDS16(g, l) __builtin_amdgcn_global_load_lds( \
  (__attribute__((address_space(1))) void*)(g),             \
  (__attribute__((address_space(3))) void*)(l), 16, 0, 0)

// ---------- fp32 -> bf16 convert, 4 elems/thread ----------
__global__ __launch_bounds__(256) void f2b4_kernel(const float* __restrict__ in,
                                                   short* __restrict__ out, int n4) {
  int i = blockIdx.x * 256 + threadIdx.x;
  if (i >= n4) return;
  float4 v = ((const float4*)in)[i];
  short4 o = make_short4(f2b(v.x), f2b(v.y), f2b(v.z), f2b(v.w));
  ((short4*)out)[i] = o;
}

// ---------- GEMM: C[M,N] = A[M,K] @ W[N,K]^T + bias  (m97 structure) ----------
template<int OUT_BF16>
__global__ __launch_bounds__(256)
void gemm_bt_kernel(const short* __restrict__ A, const short* __restrict__ W,
                    const float* __restrict__ bias, void* __restrict__ Cout,
                    int M, int N, int K)
{
  __shared__ short sA[128 * 32];
  __shared__ short sB[128 * 32];
  int nbn = N >> 7;
  int nwg = gridDim.x;
  int wg = blockIdx.x;
  int cpx = nwg >> 3;                       // nwg % 8 == 0 by construction
  wg = (wg & 7) * cpx + (wg >> 3);          // bijective XCD swizzle
  int bm = wg / nbn, bn = wg % nbn;
  int tid = threadIdx.x, wid = tid >> 6, lane = tid & 63;
  int wr = wid >> 1, wc = wid & 1;
  int lr = lane & 15, lg = lane >> 4;
  int srow = lane >> 2;                     // staging: row within 16-row chunk
  int skk = (lane & 3) * 8;                 // staging: k offset (elems)
  f32x4 acc[4][4] = {};
  const size_t baseA = (size_t)bm * 128 * K;
  const size_t baseW = (size_t)bn * 128 * K;

  for (int k0 = 0; k0 < K; k0 += 32) {
#pragma unroll
    for (int i = 0; i < 2; ++i) {
      int c = wid + i * 4;                  // chunk 0..7, 16 rows each
      int r = c * 16 + srow;
      GLOAD_LDS16(A + baseA + (size_t)r * K + k0 + skk, &sA[c * 512]);
      GLOAD_LDS16(W + baseW + (size_t)r * K + k0 + skk, &sB[c * 512]);
    }
    asm volatile("s_waitcnt vmcnt(0)" ::: "memory");
    __syncthreads();
    bf16x8 av[4], bv[4];
#pragma unroll
    for (int m = 0; m < 4; ++m) av[m] = *(const bf16x8*)&sA[(wr * 64 + m * 16 + lr) * 32 + lg * 8];
#pragma unroll
    for (int n = 0; n < 4; ++n) bv[n] = *(const bf16x8*)&sB[(wc * 64 + n * 16 + lr) * 32 + lg * 8];
#pragma unroll
    for (int m = 0; m < 4; ++m)
#pragma unroll
      for (int n = 0; n < 4; ++n)
        acc[m][n] = __builtin_amdgcn_mfma_f32_16x16x32_bf16(av[m], bv[n], acc[m][n], 0, 0, 0);
    __syncthreads();
  }

  int row0 = bm * 128 + wr * 64, col0 = bn * 128 + wc * 64;
#pragma unroll
  for (int n = 0; n < 4; ++n) {
    int col = col0 + n * 16 + lr;
    float bb = bias[col];
#pragma unroll
    for (int m = 0; m < 4; ++m) {
#pragma unroll
      for (int j = 0; j < 4; ++j) {
        int row = row0 + m * 16 + lg * 4 + j;   // C: col=lane&15, row=(lane>>4)*4+reg
        float v = acc[m][n][j] + bb;
        if (OUT_BF16) ((short*)Cout)[(size_t)row * N + col] = f2b(v);
        else          ((float*)Cout)[(size_t)row * N + col] = v;
      }
    }
  }
}

// ---------- fused rmsnorm(q 1536) + rmsnorm(kv 512) + k_pe rope ----------
__global__ __launch_bounds__(256)
void norm_rope_kernel(const float* __restrict__ c1, const float* __restrict__ qw,
                      const float* __restrict__ kvw, const float* __restrict__ fcos,
                      const float* __restrict__ fsin, short* __restrict__ qan,
                      short* __restrict__ kvn, short* __restrict__ kpe)
{
  int row = blockIdx.x;
  int s = row & (SLEN - 1);
  const float* r = c1 + (size_t)row * 2176;
  int tid = threadIdx.x, wid = tid >> 6, lane = tid & 63;
  float vq[6], vk[2];
  float sq = 0.f, sk = 0.f;
#pragma unroll
  for (int i = 0; i < 6; ++i) { vq[i] = r[tid + i * 256]; sq += vq[i] * vq[i]; }
#pragma unroll
  for (int i = 0; i < 2; ++i) { vk[i] = r[1536 + tid + i * 256]; sk += vk[i] * vk[i]; }
#pragma unroll
  for (int off = 32; off > 0; off >>= 1) {
    sq += __shfl_xor(sq, off, 64);
    sk += __shfl_xor(sk, off, 64);
  }
  __shared__ float red[2][4];
  if (lane == 0) { red[0][wid] = sq; red[1][wid] = sk; }
  __syncthreads();
  sq = red[0][0] + red[0][1] + red[0][2] + red[0][3];
  sk = red[1][0] + red[1][1] + red[1][2] + red[1][3];
  float rq = rsqrtf(sq * (1.f / 1536.f) + RMS_EPS);
  float rk = rsqrtf(sk * (1.f / 512.f) + RMS_EPS);
#pragma unroll
  for (int i = 0; i < 6; ++i) qan[(size_t)row * 1536 + tid + i * 256] = f2b(vq[i] * rq * qw[tid + i * 256]);
#pragma unroll
  for (int i = 0; i < 2; ++i) kvn[(size_t)row * 512 + tid + i * 256] = f2b(vk[i] * rk * kvw[tid + i * 256]);
  if (tid < 32) {
    float xr = r[2048 + tid * 2], xi = r[2048 + tid * 2 + 1];
    float c = fcos[s * 32 + tid], sn = fsin[s * 32 + tid];
    kpe[(size_t)row * 64 + tid * 2]     = f2b(xr * c - xi * sn);
    kpe[(size_t)row * 64 + tid * 2 + 1] = f2b(xr * sn + xi * c);
  }
}

// ---------- in-place rope on q_pe columns of q_full [4096][3072] ----------
__global__ __launch_bounds__(256)
void rope_q_kernel(short* __restrict__ qf, const float* __restrict__ fcos,
                   const float* __restrict__ fsin)
{
  int idx = blockIdx.x * 256 + threadIdx.x;  // 4096*16*32 exact
  int pr = idx & 31; int h = (idx >> 5) & 15; int row = idx >> 9;
  int s = row & (SLEN - 1);
  short2* p = (short2*)(qf + (size_t)row * 3072 + h * 192 + 128 + pr * 2);
  short2 v = *p;
  float xr = b2f(v.x), xi = b2f(v.y);
  float c = fcos[s * 32 + pr], sn = fsin[s * 32 + pr];
  v.x = f2b(xr * c - xi * sn);
  v.y = f2b(xr * sn + xi * c);
  *p = v;
}

// ---------- causal flash attention ----------
// q_full [4096][3072] (h*192 + d), kv_full [4096][4096] (h*256: 128 k_nope + 128 v),
// kpe [4096][64], obuf [4096][2048] (h*128 + d)
__global__ __launch_bounds__(256)
void attn_kernel(const short* __restrict__ qf, const short* __restrict__ kvf,
                 const short* __restrict__ kpe, short* __restrict__ obuf)
{
  __shared__ short sK[64 * 200];       // [t][0..191], stride 200 (2-way banks)
  __shared__ short sVt[128 * 72];      // [d][t], stride 72
  __shared__ short sP[4][16 * 72];     // per-wave P tile [row][t]
  int bid = blockIdx.x;
  int qt = bid & 31, h = (bid >> 5) & 15, b = bid >> 9;
  int base = b * SLEN;
  int tid = threadIdx.x, wid = tid >> 6, lane = tid & 63;
  int lr = lane & 15, lg = lane >> 4;
  int qrow = base + qt * 64 + wid * 16;

  bf16x8 qfrag[6];
  {
    const short* qp = qf + (size_t)(qrow + lr) * 3072 + h * 192;
#pragma unroll
    for (int kc = 0; kc < 6; ++kc) qfrag[kc] = *(const bf16x8*)(qp + kc * 32 + lg * 8);
  }
  f32x4 oacc[8] = {};
  float m_i[4], l_i[4];
#pragma unroll
  for (int j = 0; j < 4; ++j) { m_i[j] = -1e30f; l_i[j] = 0.f; }
  int srow0 = qt * 64 + wid * 16 + lg * 4;
  int ntiles = qt + 1;
  // staging assignments
  int str = tid >> 2, sp4 = tid & 3;            // K/pe: 4 threads per t-row
  int tpair = tid & 31, d0v = (tid >> 5) * 16;  // V: 2 t per thread, 16 d
  short* sPw = sP[wid];

  for (int it = 0; it < ntiles; ++it) {
    int t0 = it * 64;
    { // ---- stage K (nope + pe) ----
      const short* src = kvf + (size_t)(base + t0 + str) * 4096 + h * 256 + sp4 * 32;
      short* dst = &sK[str * 200 + sp4 * 32];
#pragma unroll
      for (int i = 0; i < 4; ++i) *(bf16x8*)(dst + i * 8) = *(const bf16x8*)(src + i * 8);
      const short* srcp = kpe + (size_t)(base + t0 + str) * 64 + sp4 * 16;
      short* dstp = &sK[str * 200 + 128 + sp4 * 16];
#pragma unroll
      for (int i = 0; i < 2; ++i) *(bf16x8*)(dstp + i * 8) = *(const bf16x8*)(srcp + i * 8);
      // ---- stage V transposed, packed pairs along t ----
      int tv = tpair * 2;
      const short* sv0 = kvf + (size_t)(base + t0 + tv) * 4096 + h * 256 + 128 + d0v;
      const short* sv1 = sv0 + 4096;
      bf16x8 va0 = *(const bf16x8*)(sv0);
      bf16x8 va1 = *(const bf16x8*)(sv0 + 8);
      bf16x8 vb0 = *(const bf16x8*)(sv1);
      bf16x8 vb1 = *(const bf16x8*)(sv1 + 8);
#pragma unroll
      for (int i = 0; i < 8; ++i) {
        unsigned w0 = (unsigned)(unsigned short)va0[i] | ((unsigned)(unsigned short)vb0[i] << 16);
        *((unsigned*)(sVt + (size_t)(d0v + i) * 72) + tpair) = w0;
        unsigned w1 = (unsigned)(unsigned short)va1[i] | ((unsigned)(unsigned short)vb1[i] << 16);
        *((unsigned*)(sVt + (size_t)(d0v + 8 + i) * 72) + tpair) = w1;
      }
    }
    __syncthreads();

    // ---- scores: S = Q K^T ----
    f32x4 sacc[4] = {};
#pragma unroll
    for (int tt = 0; tt < 4; ++tt) {
#pragma unroll
      for (int kc = 0; kc < 6; ++kc) {
        bf16x8 kf = *(const bf16x8*)&sK[(tt * 16 + lr) * 200 + kc * 32 + lg * 8];
        sacc[tt] = __builtin_amdgcn_mfma_f32_16x16x32_bf16(qfrag[kc], kf, sacc[tt], 0, 0, 0);
      }
    }
    // ---- online softmax (fp32) ----
    float p[4][4], rmax[4];
#pragma unroll
    for (int j = 0; j < 4; ++j) rmax[j] = -1e30f;
#pragma unroll
    for (int tt = 0; tt < 4; ++tt) {
      int t = t0 + tt * 16 + lr;
#pragma unroll
      for (int j = 0; j < 4; ++j) {
        float x = sacc[tt][j] * SCALE_QK;
        if (t > srow0 + j) x = -1e30f;
        p[tt][j] = x;
        rmax[j] = fmaxf(rmax[j], x);
      }
    }
#pragma unroll
    for (int off = 1; off < 16; off <<= 1)
#pragma unroll
      for (int j = 0; j < 4; ++j) rmax[j] = fmaxf(rmax[j], __shfl_xor(rmax[j], off, 64));
    float sf[4], rsum[4];
#pragma unroll
    for (int j = 0; j < 4; ++j) {
      float mn = fmaxf(m_i[j], rmax[j]);
      sf[j] = __expf(m_i[j] - mn);
      m_i[j] = mn;
      rsum[j] = 0.f;
    }
#pragma unroll
    for (int tt = 0; tt < 4; ++tt)
#pragma unroll
      for (int j = 0; j < 4; ++j) {
        float e = __expf(p[tt][j] - m_i[j]);
        p[tt][j] = e;
        rsum[j] += e;
      }
#pragma unroll
    for (int off = 1; off < 16; off <<= 1)
#pragma unroll
      for (int j = 0; j < 4; ++j) rsum[j] += __shfl_xor(rsum[j], off, 64);
#pragma unroll
    for (int j = 0; j < 4; ++j) l_i[j] = l_i[j] * sf[j] + rsum[j];
#pragma unroll
    for (int dt = 0; dt < 8; ++dt)
#pragma unroll
      for (int j = 0; j < 4; ++j) oacc[dt][j] *= sf[j];
    // ---- P -> LDS (wave-private), then PV ----
#pragma unroll
    for (int tt = 0; tt < 4; ++tt)
#pragma unroll
      for (int j = 0; j < 4; ++j)
        sPw[(lg * 4 + j) * 72 + tt * 16 + lr] = f2b(p[tt][j]);
    asm volatile("s_waitcnt lgkmcnt(0)" ::: "memory");
    bf16x8 pf[2];
#pragma unroll
    for (int kc = 0; kc < 2; ++kc) pf[kc] = *(const bf16x8*)&sPw[lr * 72 + kc * 32 + lg * 8];
#pragma unroll
    for (int dt = 0; dt < 8; ++dt) {
#pragma unroll
      for (int kc = 0; kc < 2; ++kc) {
        bf16x8 vf = *(const bf16x8*)&sVt[(dt * 16 + lr) * 72 + kc * 32 + lg * 8];
        oacc[dt] = __builtin_amdgcn_mfma_f32_16x16x32_bf16(pf[kc], vf, oacc[dt], 0, 0, 0);
      }
    }
    __syncthreads();
  }

  float inv[4];
#pragma unroll
  for (int j = 0; j < 4; ++j) inv[j] = 1.f / l_i[j];
#pragma unroll
  for (int dt = 0; dt < 8; ++dt)
#pragma unroll
    for (int j = 0; j < 4; ++j) {
      int row = qrow + lg * 4 + j;
      obuf[(size_t)row * 2048 + h * 128 + dt * 16 + lr] = f2b(oacc[dt][j] * inv[j]);
    }
}

// ---------- launch ----------
extern "C" void kernel_launch(void* const* d_in, const int* in_sizes, int n_in,
                              void* d_out, int out_size, void* d_ws, size_t ws_size,
                              hipStream_t stream)
{
  const float* x    = (const float*)d_in[0];
  const float* fcos = (const float*)d_in[1];
  const float* fsin = (const float*)d_in[2];
  // d_in[3] mask: causal, implemented directly
  const float* wqa   = (const float*)d_in[4];
  const float* wqab  = (const float*)d_in[5];
  const float* qnw   = (const float*)d_in[6];
  const float* wqb   = (const float*)d_in[7];
  const float* wqbb  = (const float*)d_in[8];
  const float* wkva  = (const float*)d_in[9];
  const float* wkvab = (const float*)d_in[10];
  const float* kvnw  = (const float*)d_in[11];
  const float* wkvb  = (const float*)d_in[12];
  const float* wkvbb = (const float*)d_in[13];
  const float* wo    = (const float*)d_in[14];
  const float* wob   = (const float*)d_in[15];
  float* out = (float*)d_out;

  char* ws = (char*)d_ws;
  size_t off = 0;
  auto alloc = [&](size_t bytes) {
    char* p = ws + off;
    off += (bytes + 255) & ~(size_t)255;
    return p;
  };
  short* xb     = (short*)alloc(4096ull * 2048 * 2);
  short* w1     = (short*)alloc(2176ull * 2048 * 2);   // [wq_a ; wkv_a ; zero-pad] bf16
  float* b1     = (float*)alloc(2176 * 4);
  short* wqb16  = (short*)alloc(3072ull * 1536 * 2);
  short* wkvb16 = (short*)alloc(4096ull * 512 * 2);
  short* wob16  = (short*)alloc(2048ull * 2048 * 2);
  float* c1     = (float*)alloc(4096ull * 2176 * 4);   // [q_a | kv_c | k_pe_raw]
  short* qan    = (short*)alloc(4096ull * 1536 * 2);
  short* kvn    = (short*)alloc(4096ull * 512 * 2);
  short* kpe    = (short*)alloc(4096ull * 64 * 2);
  short* qfull  = (short*)alloc(4096ull * 3072 * 2);
  short* kvfull = (short*)alloc(4096ull * 4096 * 2);
  short* obuf   = (short*)alloc(4096ull * 2048 * 2);
  (void)ws_size; (void)in_sizes; (void)n_in; (void)out_size;

  // converts
  f2b4_kernel<<<8192, 256, 0, stream>>>(x, xb, 2097152);
  f2b4_kernel<<<3072, 256, 0, stream>>>(wqa, w1, 786432);
  f2b4_kernel<<<1152, 256, 0, stream>>>(wkva, w1 + 1536ull * 2048, 294912);
  hipMemsetAsync(w1 + 2112ull * 2048, 0, 64ull * 2048 * 2, stream);
  hipMemcpyAsync(b1, wqab, 1536 * 4, hipMemcpyDeviceToDevice, stream);
  hipMemcpyAsync(b1 + 1536, wkvab, 576 * 4, hipMemcpyDeviceToDevice, stream);
  hipMemsetAsync(b1 + 2112, 0, 64 * 4, stream);
  f2b4_kernel<<<4608, 256, 0, stream>>>(wqb, wqb16, 1179648);
  f2b4_kernel<<<2048, 256, 0, stream>>>(wkvb, wkvb16, 524288);
  f2b4_kernel<<<4096, 256, 0, stream>>>(wo, wob16, 1048576);

  // pipeline
  gemm_bt_kernel<0><<<544, 256, 0, stream>>>(xb, w1, b1, c1, 4096, 2176, 2048);
  norm_rope_kernel<<<4096, 256, 0, stream>>>(c1, qnw, kvnw, fcos, fsin, qan, kvn, kpe);
  gemm_bt_kernel<1><<<768, 256, 0, stream>>>(qan, wqb16, wqbb, qfull, 4096, 3072, 1536);
  gemm_bt_kernel<1><<<1024, 256, 0, stream>>>(kvn, wkvb16, wkvbb, kvfull, 4096, 4096, 512);
  rope_q_kernel<<<8192, 256, 0, stream>>>(qfull, fcos, fsin);
  attn_kernel<<<1024, 256, 0, stream>>>(qfull, kvfull, kpe, obuf);
  gemm_bt_kernel<0><<<512, 256, 0, stream>>>(obuf, wob16, wob, out, 4096, 2048, 2048);
}

// Round 4
// 563.625 us; speedup vs baseline: 1.1917x; 1.1917x over previous
//
#include <hip/hip_runtime.h>

// ---------- constants ----------
#define SLEN 2048
#define NROW 4096           // B*S
#define NH   16
#define SCALE_QK 0.07216878364870322f   // 192^-0.5
#define RMS_EPS 1.1920928955078125e-07f

typedef __attribute__((ext_vector_type(8))) short bf16x8;
typedef __attribute__((ext_vector_type(4))) float f32x4;

__device__ __forceinline__ float b2f(short s) {
  union { float f; unsigned u; } x; x.u = ((unsigned)(unsigned short)s) << 16; return x.f;
}
__device__ __forceinline__ short f2b(float f) {
  union { float f; unsigned u; } x; x.f = f;
  unsigned r = x.u + 0x7FFFu + ((x.u >> 16) & 1u);   // RNE
  return (short)(r >> 16);
}

#define GLOAD_LDS16(g, l) __builtin_amdgcn_global_load_lds( \
  (__attribute__((address_space(1))) void*)(g),             \
  (__attribute__((address_space(3))) void*)(l), 16, 0, 0)

// ---------- fp32 -> bf16 convert, 4 elems/thread ----------
__global__ __launch_bounds__(256) void f2b4_kernel(const float* __restrict__ in,
                                                   short* __restrict__ out, int n4) {
  int i = blockIdx.x * 256 + threadIdx.x;
  if (i >= n4) return;
  float4 v = ((const float4*)in)[i];
  short4 o = make_short4(f2b(v.x), f2b(v.y), f2b(v.z), f2b(v.w));
  ((short4*)out)[i] = o;
}

// ---------- GEMM: C[M,N] = A[M,K] @ W[N,K]^T + bias  (m97 structure) ----------
template<int OUT_BF16>
__global__ __launch_bounds__(256)
void gemm_bt_kernel(const short* __restrict__ A, const short* __restrict__ W,
                    const float* __restrict__ bias, void* __restrict__ Cout,
                    int M, int N, int K)
{
  __shared__ short sA[128 * 32];
  __shared__ short sB[128 * 32];
  int nbn = N >> 7;
  int nwg = gridDim.x;
  int wg = blockIdx.x;
  int cpx = nwg >> 3;                       // nwg % 8 == 0 by construction
  wg = (wg & 7) * cpx + (wg >> 3);          // bijective XCD swizzle
  int bm = wg / nbn, bn = wg % nbn;
  int tid = threadIdx.x, wid = tid >> 6, lane = tid & 63;
  int wr = wid >> 1, wc = wid & 1;
  int lr = lane & 15, lg = lane >> 4;
  int srow = lane >> 2;                     // staging: row within 16-row chunk
  int skk = (lane & 3) * 8;                 // staging: k offset (elems)
  f32x4 acc[4][4] = {};
  const size_t baseA = (size_t)bm * 128 * K;
  const size_t baseW = (size_t)bn * 128 * K;

  for (int k0 = 0; k0 < K; k0 += 32) {
#pragma unroll
    for (int i = 0; i < 2; ++i) {
      int c = wid + i * 4;                  // chunk 0..7, 16 rows each
      int r = c * 16 + srow;
      GLOAD_LDS16(A + baseA + (size_t)r * K + k0 + skk, &sA[c * 512]);
      GLOAD_LDS16(W + baseW + (size_t)r * K + k0 + skk, &sB[c * 512]);
    }
    asm volatile("s_waitcnt vmcnt(0)" ::: "memory");
    __syncthreads();
    bf16x8 av[4], bv[4];
#pragma unroll
    for (int m = 0; m < 4; ++m) av[m] = *(const bf16x8*)&sA[(wr * 64 + m * 16 + lr) * 32 + lg * 8];
#pragma unroll
    for (int n = 0; n < 4; ++n) bv[n] = *(const bf16x8*)&sB[(wc * 64 + n * 16 + lr) * 32 + lg * 8];
#pragma unroll
    for (int m = 0; m < 4; ++m)
#pragma unroll
      for (int n = 0; n < 4; ++n)
        acc[m][n] = __builtin_amdgcn_mfma_f32_16x16x32_bf16(av[m], bv[n], acc[m][n], 0, 0, 0);
    __syncthreads();
  }

  int row0 = bm * 128 + wr * 64, col0 = bn * 128 + wc * 64;
#pragma unroll
  for (int n = 0; n < 4; ++n) {
    int col = col0 + n * 16 + lr;
    float bb = bias[col];
#pragma unroll
    for (int m = 0; m < 4; ++m) {
#pragma unroll
      for (int j = 0; j < 4; ++j) {
        int row = row0 + m * 16 + lg * 4 + j;   // C: col=lane&15, row=(lane>>4)*4+reg
        float v = acc[m][n][j] + bb;
        if (OUT_BF16) ((short*)Cout)[(size_t)row * N + col] = f2b(v);
        else          ((float*)Cout)[(size_t)row * N + col] = v;
      }
    }
  }
}

// ---------- fused rmsnorm(q 1536) + rmsnorm(kv 512) + k_pe rope ----------
__global__ __launch_bounds__(256)
void norm_rope_kernel(const float* __restrict__ c1, const float* __restrict__ qw,
                      const float* __restrict__ kvw, const float* __restrict__ fcos,
                      const float* __restrict__ fsin, short* __restrict__ qan,
                      short* __restrict__ kvn, short* __restrict__ kpe)
{
  int row = blockIdx.x;
  int s = row & (SLEN - 1);
  const float* r = c1 + (size_t)row * 2176;
  int tid = threadIdx.x, wid = tid >> 6, lane = tid & 63;
  float vq[6], vk[2];
  float sq = 0.f, sk = 0.f;
#pragma unroll
  for (int i = 0; i < 6; ++i) { vq[i] = r[tid + i * 256]; sq += vq[i] * vq[i]; }
#pragma unroll
  for (int i = 0; i < 2; ++i) { vk[i] = r[1536 + tid + i * 256]; sk += vk[i] * vk[i]; }
#pragma unroll
  for (int off = 32; off > 0; off >>= 1) {
    sq += __shfl_xor(sq, off, 64);
    sk += __shfl_xor(sk, off, 64);
  }
  __shared__ float red[2][4];
  if (lane == 0) { red[0][wid] = sq; red[1][wid] = sk; }
  __syncthreads();
  sq = red[0][0] + red[0][1] + red[0][2] + red[0][3];
  sk = red[1][0] + red[1][1] + red[1][2] + red[1][3];
  float rq = rsqrtf(sq * (1.f / 1536.f) + RMS_EPS);
  float rk = rsqrtf(sk * (1.f / 512.f) + RMS_EPS);
#pragma unroll
  for (int i = 0; i < 6; ++i) qan[(size_t)row * 1536 + tid + i * 256] = f2b(vq[i] * rq * qw[tid + i * 256]);
#pragma unroll
  for (int i = 0; i < 2; ++i) kvn[(size_t)row * 512 + tid + i * 256] = f2b(vk[i] * rk * kvw[tid + i * 256]);
  if (tid < 32) {
    float xr = r[2048 + tid * 2], xi = r[2048 + tid * 2 + 1];
    float c = fcos[s * 32 + tid], sn = fsin[s * 32 + tid];
    kpe[(size_t)row * 64 + tid * 2]     = f2b(xr * c - xi * sn);
    kpe[(size_t)row * 64 + tid * 2 + 1] = f2b(xr * sn + xi * c);
  }
}

// ---------- in-place rope on q_pe columns of q_full [4096][3072] ----------
__global__ __launch_bounds__(256)
void rope_q_kernel(short* __restrict__ qf, const float* __restrict__ fcos,
                   const float* __restrict__ fsin)
{
  int idx = blockIdx.x * 256 + threadIdx.x;  // 4096*16*32 exact
  int pr = idx & 31; int h = (idx >> 5) & 15; int row = idx >> 9;
  int s = row & (SLEN - 1);
  short2* p = (short2*)(qf + (size_t)row * 3072 + h * 192 + 128 + pr * 2);
  short2 v = *p;
  float xr = b2f(v.x), xi = b2f(v.y);
  float c = fcos[s * 32 + pr], sn = fsin[s * 32 + pr];
  v.x = f2b(xr * c - xi * sn);
  v.y = f2b(xr * sn + xi * c);
  *p = v;
}

// ---------- online softmax helper (16 q-rows per wave, 64 t per tile) ----------
__device__ __forceinline__ void softmax16(f32x4* sacc, float p[4][4], float* m_i,
                                          float* l_i, f32x4* oacc, int t0, int srow0, int lr)
{
  float rmax[4];
#pragma unroll
  for (int j = 0; j < 4; ++j) rmax[j] = -1e30f;
#pragma unroll
  for (int tt = 0; tt < 4; ++tt) {
    int t = t0 + tt * 16 + lr;
#pragma unroll
    for (int j = 0; j < 4; ++j) {
      float x = sacc[tt][j] * SCALE_QK;
      if (t > srow0 + j) x = -1e30f;
      p[tt][j] = x;
      rmax[j] = fmaxf(rmax[j], x);
    }
  }
#pragma unroll
  for (int off = 1; off < 16; off <<= 1)
#pragma unroll
    for (int j = 0; j < 4; ++j) rmax[j] = fmaxf(rmax[j], __shfl_xor(rmax[j], off, 64));
  bool grow = false;
#pragma unroll
  for (int j = 0; j < 4; ++j) grow = grow || (rmax[j] > m_i[j] + 8.f);
  if (__any((int)grow)) {          // defer-max: skip rescale on small growth
    float sf[4];
#pragma unroll
    for (int j = 0; j < 4; ++j) {
      float mn = fmaxf(m_i[j], rmax[j]);
      sf[j] = __expf(m_i[j] - mn);
      m_i[j] = mn;
      l_i[j] *= sf[j];
    }
#pragma unroll
    for (int dt = 0; dt < 8; ++dt)
#pragma unroll
      for (int j = 0; j < 4; ++j) oacc[dt][j] *= sf[j];
  }
  float rsum[4] = {0.f, 0.f, 0.f, 0.f};
#pragma unroll
  for (int tt = 0; tt < 4; ++tt)
#pragma unroll
    for (int j = 0; j < 4; ++j) {
      float e = __expf(p[tt][j] - m_i[j]);
      p[tt][j] = e;
      rsum[j] += e;
    }
#pragma unroll
  for (int off = 1; off < 16; off <<= 1)
#pragma unroll
    for (int j = 0; j < 4; ++j) rsum[j] += __shfl_xor(rsum[j], off, 64);
#pragma unroll
  for (int j = 0; j < 4; ++j) l_i[j] += rsum[j];
}

// ---------- causal flash attention, paired q-tiles (i, 31-i) ----------
// grid 512 = b(2) * h(16) * pair(16); each block: qtA=i (small), qtB=31-i (large).
// Shared KV staging; constant 33 MFMA-steps/block -> balanced.
__global__ __launch_bounds__(256, 2)
void attn_kernel(const short* __restrict__ qf, const short* __restrict__ kvf,
                 const short* __restrict__ kpe, short* __restrict__ obuf)
{
  __shared__ short sK[64 * 200];       // [t][0..191], stride 200
  __shared__ short sVt[128 * 72];      // [d][t], stride 72
  __shared__ short sPA[4][16 * 72];
  __shared__ short sPB[4][16 * 72];
  int bid = blockIdx.x;
  bid = (bid & 7) * 64 + (bid >> 3);   // bijective XCD swizzle (512 % 8 == 0)
  int i = bid & 15, h = (bid >> 4) & 15, b = bid >> 8;
  int qtA = i, qtB = 31 - i;
  int base = b * SLEN;
  int tid = threadIdx.x, wid = tid >> 6, lane = tid & 63;
  int lr = lane & 15, lg = lane >> 4;
  int qrowA = base + qtA * 64 + wid * 16;
  int qrowB = base + qtB * 64 + wid * 16;

  bf16x8 qfragA[6], qfragB[6];
  {
    const short* qpA = qf + (size_t)(qrowA + lr) * 3072 + h * 192;
    const short* qpB = qf + (size_t)(qrowB + lr) * 3072 + h * 192;
#pragma unroll
    for (int kc = 0; kc < 6; ++kc) {
      qfragA[kc] = *(const bf16x8*)(qpA + kc * 32 + lg * 8);
      qfragB[kc] = *(const bf16x8*)(qpB + kc * 32 + lg * 8);
    }
  }
  f32x4 oaccA[8] = {}, oaccB[8] = {};
  float mA[4], lA[4], mB[4], lB[4];
#pragma unroll
  for (int j = 0; j < 4; ++j) { mA[j] = mB[j] = -1e30f; lA[j] = lB[j] = 0.f; }
  int srow0A = qtA * 64 + wid * 16 + lg * 4;
  int srow0B = qtB * 64 + wid * 16 + lg * 4;
  // staging assignments
  int str = tid >> 2, sp4 = tid & 3;            // K/pe: 4 threads per t-row
  int tpair = tid & 31, d0v = (tid >> 5) * 16;  // V: 2 t per thread, 16 d
  short* sPAw = sPA[wid];
  short* sPBw = sPB[wid];

  for (int it = 0; it <= qtB; ++it) {
    int t0 = it * 64;
    { // ---- stage K (nope + pe) ----
      const short* src = kvf + (size_t)(base + t0 + str) * 4096 + h * 256 + sp4 * 32;
      short* dst = &sK[str * 200 + sp4 * 32];
#pragma unroll
      for (int k = 0; k < 4; ++k) *(bf16x8*)(dst + k * 8) = *(const bf16x8*)(src + k * 8);
      const short* srcp = kpe + (size_t)(base + t0 + str) * 64 + sp4 * 16;
      short* dstp = &sK[str * 200 + 128 + sp4 * 16];
#pragma unroll
      for (int k = 0; k < 2; ++k) *(bf16x8*)(dstp + k * 8) = *(const bf16x8*)(srcp + k * 8);
      // ---- stage V transposed, packed pairs along t ----
      int tv = tpair * 2;
      const short* sv0 = kvf + (size_t)(base + t0 + tv) * 4096 + h * 256 + 128 + d0v;
      const short* sv1 = sv0 + 4096;
      bf16x8 va0 = *(const bf16x8*)(sv0);
      bf16x8 va1 = *(const bf16x8*)(sv0 + 8);
      bf16x8 vb0 = *(const bf16x8*)(sv1);
      bf16x8 vb1 = *(const bf16x8*)(sv1 + 8);
#pragma unroll
      for (int k = 0; k < 8; ++k) {
        unsigned w0 = (unsigned)(unsigned short)va0[k] | ((unsigned)(unsigned short)vb0[k] << 16);
        *((unsigned*)(sVt + (size_t)(d0v + k) * 72) + tpair) = w0;
        unsigned w1 = (unsigned)(unsigned short)va1[k] | ((unsigned)(unsigned short)vb1[k] << 16);
        *((unsigned*)(sVt + (size_t)(d0v + 8 + k) * 72) + tpair) = w1;
      }
    }
    __syncthreads();
    bool doA = (it <= qtA);

    // ---- scores ----
    f32x4 saccB[4] = {};
#pragma unroll
    for (int tt = 0; tt < 4; ++tt)
#pragma unroll
      for (int kc = 0; kc < 6; ++kc) {
        bf16x8 kf = *(const bf16x8*)&sK[(tt * 16 + lr) * 200 + kc * 32 + lg * 8];
        saccB[tt] = __builtin_amdgcn_mfma_f32_16x16x32_bf16(qfragB[kc], kf, saccB[tt], 0, 0, 0);
      }
    f32x4 saccA[4] = {};
    if (doA) {
#pragma unroll
      for (int tt = 0; tt < 4; ++tt)
#pragma unroll
        for (int kc = 0; kc < 6; ++kc) {
          bf16x8 kf = *(const bf16x8*)&sK[(tt * 16 + lr) * 200 + kc * 32 + lg * 8];
          saccA[tt] = __builtin_amdgcn_mfma_f32_16x16x32_bf16(qfragA[kc], kf, saccA[tt], 0, 0, 0);
        }
    }
    // ---- softmax + P writes ----
    {
      float pB[4][4];
      softmax16(saccB, pB, mB, lB, oaccB, t0, srow0B, lr);
#pragma unroll
      for (int tt = 0; tt < 4; ++tt)
#pragma unroll
        for (int j = 0; j < 4; ++j)
          sPBw[(lg * 4 + j) * 72 + tt * 16 + lr] = f2b(pB[tt][j]);
    }
    if (doA) {
      float pA[4][4];
      softmax16(saccA, pA, mA, lA, oaccA, t0, srow0A, lr);
#pragma unroll
      for (int tt = 0; tt < 4; ++tt)
#pragma unroll
        for (int j = 0; j < 4; ++j)
          sPAw[(lg * 4 + j) * 72 + tt * 16 + lr] = f2b(pA[tt][j]);
    }
    asm volatile("s_waitcnt lgkmcnt(0)" ::: "memory");
    // ---- PV ----
    {
      bf16x8 pf[2];
#pragma unroll
      for (int kc = 0; kc < 2; ++kc) pf[kc] = *(const bf16x8*)&sPBw[lr * 72 + kc * 32 + lg * 8];
#pragma unroll
      for (int dt = 0; dt < 8; ++dt)
#pragma unroll
        for (int kc = 0; kc < 2; ++kc) {
          bf16x8 vf = *(const bf16x8*)&sVt[(dt * 16 + lr) * 72 + kc * 32 + lg * 8];
          oaccB[dt] = __builtin_amdgcn_mfma_f32_16x16x32_bf16(pf[kc], vf, oaccB[dt], 0, 0, 0);
        }
    }
    if (doA) {
      bf16x8 pf[2];
#pragma unroll
      for (int kc = 0; kc < 2; ++kc) pf[kc] = *(const bf16x8*)&sPAw[lr * 72 + kc * 32 + lg * 8];
#pragma unroll
      for (int dt = 0; dt < 8; ++dt)
#pragma unroll
        for (int kc = 0; kc < 2; ++kc) {
          bf16x8 vf = *(const bf16x8*)&sVt[(dt * 16 + lr) * 72 + kc * 32 + lg * 8];
          oaccA[dt] = __builtin_amdgcn_mfma_f32_16x16x32_bf16(pf[kc], vf, oaccA[dt], 0, 0, 0);
        }
    }
    __syncthreads();
  }

  float invA[4], invB[4];
#pragma unroll
  for (int j = 0; j < 4; ++j) { invA[j] = 1.f / lA[j]; invB[j] = 1.f / lB[j]; }
#pragma unroll
  for (int dt = 0; dt < 8; ++dt)
#pragma unroll
    for (int j = 0; j < 4; ++j) {
      int rowA = qrowA + lg * 4 + j;
      int rowB = qrowB + lg * 4 + j;
      obuf[(size_t)rowA * 2048 + h * 128 + dt * 16 + lr] = f2b(oaccA[dt][j] * invA[j]);
      obuf[(size_t)rowB * 2048 + h * 128 + dt * 16 + lr] = f2b(oaccB[dt][j] * invB[j]);
    }
}

// ---------- launch ----------
extern "C" void kernel_launch(void* const* d_in, const int* in_sizes, int n_in,
                              void* d_out, int out_size, void* d_ws, size_t ws_size,
                              hipStream_t stream)
{
  const float* x    = (const float*)d_in[0];
  const float* fcos = (const float*)d_in[1];
  const float* fsin = (const float*)d_in[2];
  // d_in[3] mask: causal, implemented directly
  const float* wqa   = (const float*)d_in[4];
  const float* wqab  = (const float*)d_in[5];
  const float* qnw   = (const float*)d_in[6];
  const float* wqb   = (const float*)d_in[7];
  const float* wqbb  = (const float*)d_in[8];
  const float* wkva  = (const float*)d_in[9];
  const float* wkvab = (const float*)d_in[10];
  const float* kvnw  = (const float*)d_in[11];
  const float* wkvb  = (const float*)d_in[12];
  const float* wkvbb = (const float*)d_in[13];
  const float* wo    = (const float*)d_in[14];
  const float* wob   = (const float*)d_in[15];
  float* out = (float*)d_out;

  char* ws = (char*)d_ws;
  size_t off = 0;
  auto alloc = [&](size_t bytes) {
    char* p = ws + off;
    off += (bytes + 255) & ~(size_t)255;
    return p;
  };
  short* xb     = (short*)alloc(4096ull * 2048 * 2);
  short* w1     = (short*)alloc(2176ull * 2048 * 2);   // [wq_a ; wkv_a ; zero-pad] bf16
  float* b1     = (float*)alloc(2176 * 4);
  short* wqb16  = (short*)alloc(3072ull * 1536 * 2);
  short* wkvb16 = (short*)alloc(4096ull * 512 * 2);
  short* wob16  = (short*)alloc(2048ull * 2048 * 2);
  float* c1     = (float*)alloc(4096ull * 2176 * 4);   // [q_a | kv_c | k_pe_raw]
  short* qan    = (short*)alloc(4096ull * 1536 * 2);
  short* kvn    = (short*)alloc(4096ull * 512 * 2);
  short* kpe    = (short*)alloc(4096ull * 64 * 2);
  short* qfull  = (short*)alloc(4096ull * 3072 * 2);
  short* kvfull = (short*)alloc(4096ull * 4096 * 2);
  short* obuf   = (short*)alloc(4096ull * 2048 * 2);
  (void)ws_size; (void)in_sizes; (void)n_in; (void)out_size;

  // converts
  f2b4_kernel<<<8192, 256, 0, stream>>>(x, xb, 2097152);
  f2b4_kernel<<<3072, 256, 0, stream>>>(wqa, w1, 786432);
  f2b4_kernel<<<1152, 256, 0, stream>>>(wkva, w1 + 1536ull * 2048, 294912);
  hipMemsetAsync(w1 + 2112ull * 2048, 0, 64ull * 2048 * 2, stream);
  hipMemcpyAsync(b1, wqab, 1536 * 4, hipMemcpyDeviceToDevice, stream);
  hipMemcpyAsync(b1 + 1536, wkvab, 576 * 4, hipMemcpyDeviceToDevice, stream);
  hipMemsetAsync(b1 + 2112, 0, 64 * 4, stream);
  f2b4_kernel<<<4608, 256, 0, stream>>>(wqb, wqb16, 1179648);
  f2b4_kernel<<<2048, 256, 0, stream>>>(wkvb, wkvb16, 524288);
  f2b4_kernel<<<4096, 256, 0, stream>>>(wo, wob16, 1048576);

  // pipeline
  gemm_bt_kernel<0><<<544, 256, 0, stream>>>(xb, w1, b1, c1, 4096, 2176, 2048);
  norm_rope_kernel<<<4096, 256, 0, stream>>>(c1, qnw, kvnw, fcos, fsin, qan, kvn, kpe);
  gemm_bt_kernel<1><<<768, 256, 0, stream>>>(qan, wqb16, wqbb, qfull, 4096, 3072, 1536);
  gemm_bt_kernel<1><<<1024, 256, 0, stream>>>(kvn, wkvb16, wkvbb, kvfull, 4096, 4096, 512);
  rope_q_kernel<<<8192, 256, 0, stream>>>(qfull, fcos, fsin);
  attn_kernel<<<512, 256, 0, stream>>>(qfull, kvfull, kpe, obuf);
  gemm_bt_kernel<0><<<512, 256, 0, stream>>>(obuf, wob16, wob, out, 4096, 2048, 2048);
}